// Round 5
// baseline (843.336 us; speedup 1.0000x reference)
//
#include <hip/hip_runtime.h>
#include <hip/hip_bf16.h>

#define TOK   4096            // B*S
#define DDIM  1024
#define NEXP  8
#define HDIM  4096
#define KSEL  2
#define NPAIR (TOK * KSEL)    // 8192

typedef __attribute__((ext_vector_type(8))) _Float16 f16x8;
typedef __attribute__((ext_vector_type(4))) _Float16 f16x4;
typedef __attribute__((ext_vector_type(4))) float    f32x4;

__device__ __forceinline__ void gload16(const void* g, void* l) {
  __builtin_amdgcn_global_load_lds((const __attribute__((address_space(1))) void*)g,
                                   (__attribute__((address_space(3))) void*)l, 16, 0, 0);
}

__device__ __forceinline__ float gelu_tanh(float u) {
  float inner = 0.7978845608028654f * (u + 0.044715f * u * u * u);
  float t2 = __expf(2.f * inner);
  return u - u / (t2 + 1.f);     // == 0.5*u*(1+tanh(inner)), overflow-safe
}

// ---------------- router (+ fused x->fp16): one wave per token ----------------
__global__ __launch_bounds__(256) void k_router(const float* __restrict__ x,
    const float* __restrict__ rw, const float* __restrict__ rb,
    int* __restrict__ tidx, float* __restrict__ tw, int* __restrict__ counts,
    _Float16* __restrict__ xb) {
  const int t    = blockIdx.x * 4 + (threadIdx.x >> 6);
  const int lane = threadIdx.x & 63;
  const float* xr = x + (size_t)t * DDIM;
  _Float16*   xbr = xb + (size_t)t * DDIM;
  float acc[NEXP];
#pragma unroll
  for (int e = 0; e < NEXP; ++e) acc[e] = 0.f;
  for (int d0 = lane * 4; d0 < DDIM; d0 += 256) {
    const float4 xv = *(const float4*)(xr + d0);
    f16x4 hx;
    hx[0] = (_Float16)xv.x; hx[1] = (_Float16)xv.y;
    hx[2] = (_Float16)xv.z; hx[3] = (_Float16)xv.w;
    *(f16x4*)(xbr + d0) = hx;
#pragma unroll
    for (int i = 0; i < 4; ++i) {
      const float xs = (&xv.x)[i];
      const float4 r0 = *(const float4*)(rw + (size_t)(d0 + i) * NEXP);
      const float4 r1 = *(const float4*)(rw + (size_t)(d0 + i) * NEXP + 4);
      acc[0] += xs * r0.x; acc[1] += xs * r0.y; acc[2] += xs * r0.z; acc[3] += xs * r0.w;
      acc[4] += xs * r1.x; acc[5] += xs * r1.y; acc[6] += xs * r1.z; acc[7] += xs * r1.w;
    }
  }
#pragma unroll
  for (int e = 0; e < NEXP; ++e) {
    float v = acc[e];
#pragma unroll
    for (int s = 32; s; s >>= 1) v += __shfl_xor(v, s, 64);
    acc[e] = v;
  }
  if (lane == 0) {
    float lg[NEXP];
#pragma unroll
    for (int e = 0; e < NEXP; ++e) lg[e] = acc[e] + rb[e];
    int i0 = 0;
#pragma unroll
    for (int e = 1; e < NEXP; ++e) if (lg[e] > lg[i0]) i0 = e;
    int i1 = -1; float best = -3.4e38f;
#pragma unroll
    for (int e = 0; e < NEXP; ++e) {
      if (e == i0) continue;
      if (lg[e] > best) { best = lg[e]; i1 = e; }
    }
    float w0 = 1.f / (1.f + expf(lg[i1] - lg[i0]));
    tidx[t * 2]     = i0;  tidx[t * 2 + 1] = i1;
    tw[t * 2]       = w0;  tw[t * 2 + 1]   = 1.f - w0;
    atomicAdd(&counts[i0], 1);
    atomicAdd(&counts[i1], 1);
  }
}

// ---------------- scan + scatter (single block, ballot-aggregated) ----------------
__global__ __launch_bounds__(1024) void k_scan(const int* __restrict__ tidx,
                       const float* __restrict__ tw,
                       const int* __restrict__ counts, int* __restrict__ offs,
                       int* __restrict__ row_token, float* __restrict__ row_w,
                       int* __restrict__ inv) {
  __shared__ int soff[NEXP + 1];
  __shared__ int scur[NEXP];
  if (threadIdx.x == 0) {
    int run = 0;
    for (int e = 0; e < NEXP; ++e) { soff[e] = run; run += counts[e]; }
    soff[NEXP] = run;
    for (int e = 0; e <= NEXP; ++e) offs[e] = soff[e];
  }
  __syncthreads();
  if (threadIdx.x < NEXP) scur[threadIdx.x] = soff[threadIdx.x];
  __syncthreads();
  const int lane = threadIdx.x & 63;
#pragma unroll
  for (int it = 0; it < NPAIR / 1024; ++it) {
    const int p = it * 1024 + threadIdx.x;
    const int e = tidx[p];
    int pos = 0;
#pragma unroll
    for (int ee = 0; ee < NEXP; ++ee) {
      unsigned long long m = __ballot(e == ee);
      if (!m) continue;
      int base = 0;
      if (lane == 0) base = atomicAdd(&scur[ee], __popcll(m));
      base = __shfl(base, 0, 64);
      if (e == ee) pos = base + __popcll(m & ((1ull << lane) - 1ull));
    }
    row_token[pos] = p >> 1;
    row_w[pos]     = tw[p];
    inv[p]         = pos;
  }
}

// ---------------- transpose fp32 [Rr][Cc] -> fp16 [Cc][Rr], per expert ----------------
__global__ __launch_bounds__(256) void k_transpose(const float* __restrict__ in,
    _Float16* __restrict__ out, int Rr, int Cc) {
  __shared__ _Float16 tile[64][72];
  const size_t esz = (size_t)Rr * Cc;
  const float* ip = in + esz * blockIdx.z;
  _Float16*    op = out + esz * blockIdx.z;
  const int i0 = blockIdx.y * 64;
  const int j0 = blockIdx.x * 64;
  const int tx = threadIdx.x & 15, ty = threadIdx.x >> 4;
#pragma unroll
  for (int rr = 0; rr < 4; ++rr) {
    int r = ty + rr * 16;
    float4 v = *(const float4*)(ip + (size_t)(i0 + r) * Cc + j0 + tx * 4);
    tile[r][tx * 4 + 0] = (_Float16)v.x;
    tile[r][tx * 4 + 1] = (_Float16)v.y;
    tile[r][tx * 4 + 2] = (_Float16)v.z;
    tile[r][tx * 4 + 3] = (_Float16)v.w;
  }
  __syncthreads();
#pragma unroll
  for (int cc = 0; cc < 4; ++cc) {
    int c = ty + cc * 16;
    f16x4 o;
#pragma unroll
    for (int k = 0; k < 4; ++k) o[k] = tile[tx * 4 + k][c];
    *(f16x4*)(op + (size_t)(j0 + c) * Rr + i0 + tx * 4) = o;
  }
}

#define BM 128
#define BN 128
#define BKK 32

// LDS: A[3 bufs x 8K] at 0, B[3 bufs x 8K] at 24K -> 48KB. Rows of 64B = 4 slots
// of 16B; physical slot = logical ^ ((row>>1)&3) (2-way max on reads = free).

// ---------------- GEMM1: h = gelu(X_gathered @ w1t^T + b1), fp16 out ----------------
// grid 1D: id -> nx = id/(32*NEXP) (N-tile), y = r&31 (M-tile), e = r>>5.
// Same (y,e), different nx => id differs by 256 (mult of 8) => same XCD => A-panel L2 reuse.
__global__ __launch_bounds__(256) void k_gemm1(
    const _Float16* __restrict__ xb,    // [TOK][DDIM]
    const _Float16* __restrict__ w1t,   // [NEXP][HDIM][DDIM]
    const float* __restrict__ b1,       // [NEXP][HDIM]
    const int* __restrict__ offs,
    const int* __restrict__ row_token,
    _Float16* __restrict__ hbuf) {      // [NPAIR][HDIM]
  const int id = blockIdx.x;
  const int nx = id >> 8;               // id / 256
  const int r_ = id & 255;
  const int my = r_ & 31;
  const int e  = r_ >> 5;
  const int off0 = offs[e];
  const int ne   = offs[e + 1] - off0;
  const int m0   = my * BM;
  if (m0 >= ne) return;
  const int n0   = nx * BN;
  const int mrem = ne - m0;

  __shared__ __align__(16) char smem[49152];

  const int tid = threadIdx.x;
  const int wv = tid >> 6, lane = tid & 63;
  const int l15 = lane & 15;
  const int wr = wv >> 1, wc = wv & 1;

  const int rA0 = (wv * 2 + 0) * 16 + (lane >> 2);
  const int rA1 = (wv * 2 + 1) * 16 + (lane >> 2);
  const char* a_c = (const char*)xb;
  const char* b_c = (const char*)(w1t + (size_t)e * HDIM * DDIM);
  const int rc0 = (rA0 < mrem) ? rA0 : (mrem - 1);
  const int rc1 = (rA1 < mrem) ? rA1 : (mrem - 1);
  const char* ap0 = a_c + (size_t)row_token[off0 + m0 + rc0] * (DDIM * 2)
                        + (((lane & 3) ^ ((rA0 >> 1) & 3)) << 4);
  const char* ap1 = a_c + (size_t)row_token[off0 + m0 + rc1] * (DDIM * 2)
                        + (((lane & 3) ^ ((rA1 >> 1) & 3)) << 4);
  const char* bp0 = b_c + (size_t)(n0 + rA0) * (DDIM * 2)
                        + (((lane & 3) ^ ((rA0 >> 1) & 3)) << 4);
  const char* bp1 = b_c + (size_t)(n0 + rA1) * (DDIM * 2)
                        + (((lane & 3) ^ ((rA1 >> 1) & 3)) << 4);
  char* ldsA = smem;
  char* ldsB = smem + 24576;
  const int ch0 = (wv * 2 + 0) * 1024, ch1 = (wv * 2 + 1) * 1024;

  const unsigned foff = (unsigned)(((lane >> 4) ^ ((l15 >> 1) & 3)) << 4);

  f32x4 acc[4][4] = {};
  const int NT = DDIM / BKK;   // 32

  // prologue: stage ks=0 -> buf0, ks=1 -> buf1
  gload16(ap0, ldsA + ch0);        gload16(ap1, ldsA + ch1);
  gload16(bp0, ldsB + ch0);        gload16(bp1, ldsB + ch1);
  gload16(ap0 + 64, ldsA + 8192 + ch0); gload16(ap1 + 64, ldsA + 8192 + ch1);
  gload16(bp0 + 64, ldsB + 8192 + ch0); gload16(bp1 + 64, ldsB + 8192 + ch1);

  int cur = 0, nx2 = 2;
  for (int ks = 0; ks < NT; ++ks) {
    if (ks + 2 < NT) {
      const size_t kb = (size_t)(ks + 2) * 64;
      const int nb = nx2 * 8192;
      gload16(ap0 + kb, ldsA + nb + ch0); gload16(ap1 + kb, ldsA + nb + ch1);
      gload16(bp0 + kb, ldsB + nb + ch0); gload16(bp1 + kb, ldsB + nb + ch1);
      asm volatile("s_waitcnt vmcnt(8)" ::: "memory");
    } else if (ks + 1 < NT) {
      asm volatile("s_waitcnt vmcnt(4)" ::: "memory");
    } else {
      asm volatile("s_waitcnt vmcnt(0)" ::: "memory");
    }
    __builtin_amdgcn_sched_barrier(0);
    __builtin_amdgcn_s_barrier();
    const char* Ab = ldsA + cur * 8192;
    const char* Bb = ldsB + cur * 8192;
    f16x8 af[4], bfr[4];
#pragma unroll
    for (int m = 0; m < 4; ++m)
      af[m] = *(const f16x8*)(Ab + (wr * 64 + m * 16 + l15) * 64 + foff);
#pragma unroll
    for (int n = 0; n < 4; ++n)
      bfr[n] = *(const f16x8*)(Bb + (wc * 64 + n * 16 + l15) * 64 + foff);
#pragma unroll
    for (int m = 0; m < 4; ++m)
#pragma unroll
      for (int n = 0; n < 4; ++n)
        acc[m][n] = __builtin_amdgcn_mfma_f32_16x16x32_f16(af[m], bfr[n], acc[m][n], 0, 0, 0);
    __builtin_amdgcn_sched_barrier(0);
    __builtin_amdgcn_s_barrier();
    cur = (cur == 2) ? 0 : cur + 1;
    nx2 = (nx2 == 2) ? 0 : nx2 + 1;
  }

  // epilogue: bias + gelu -> restage f16 C-tile in LDS -> coalesced stores
  float bias[4];
#pragma unroll
  for (int n = 0; n < 4; ++n)
    bias[n] = b1[(size_t)e * HDIM + n0 + wc * 64 + n * 16 + l15];
#pragma unroll
  for (int m = 0; m < 4; ++m) {
#pragma unroll
    for (int j = 0; j < 4; ++j) {
      int row = wr * 64 + m * 16 + (lane >> 4) * 4 + j;
#pragma unroll
      for (int n = 0; n < 4; ++n) {
        int col = wc * 64 + n * 16 + l15;
        *(_Float16*)(smem + (row << 8) + (((col << 1) ^ ((row & 15) << 4)))) =
            (_Float16)gelu_tanh(acc[m][n][j] + bias[n]);
      }
    }
  }
  __syncthreads();
  {
    const int srow = tid >> 1, half = tid & 1;
    if (srow < mrem) {
      _Float16* hr = hbuf + (size_t)(off0 + m0 + srow) * HDIM + n0 + half * 64;
#pragma unroll
      for (int i = 0; i < 8; ++i) {
        f16x8 v = *(const f16x8*)(smem + (srow << 8) + (((half * 128 + i * 16) ^ ((srow & 15) << 4))));
        *(f16x8*)(hr + i * 8) = v;
      }
    }
  }
}

// ---------------- GEMM2 (split-K=2): ypart[kh] = H @ w2t^T ----------------
template <bool YB>
__global__ __launch_bounds__(256) void k_gemm2(
    const _Float16* __restrict__ hbuf,  // [NPAIR][HDIM]
    const _Float16* __restrict__ w2t,   // [NEXP][DDIM][HDIM]
    const float* __restrict__ b2,       // [NEXP][DDIM]
    const int* __restrict__ offs,
    const int* __restrict__ row_token,
    const float* __restrict__ row_w,
    _Float16* __restrict__ yb,          // [2][NPAIR][DDIM] partials (YB path)
    float* __restrict__ out) {          // [TOK][DDIM]      (atomic path)
  const int id = blockIdx.x;
  const int nx = id >> 9;               // id / 512, 0..7
  const int r_ = id & 511;
  const int my = r_ & 31;
  const int zz = r_ >> 5;               // 0..15
  const int e  = zz >> 1;
  const int kh = zz & 1;
  const int off0 = offs[e];
  const int ne   = offs[e + 1] - off0;
  const int m0   = my * BM;
  if (m0 >= ne) return;
  const int n0   = nx * BN;
  const int mrem = ne - m0;

  __shared__ __align__(16) char smem[49152];

  const int tid = threadIdx.x;
  const int wv = tid >> 6, lane = tid & 63;
  const int l15 = lane & 15;
  const int wr = wv >> 1, wc = wv & 1;

  const int rA0 = (wv * 2 + 0) * 16 + (lane >> 2);
  const int rA1 = (wv * 2 + 1) * 16 + (lane >> 2);
  const char* a_c = (const char*)hbuf;
  const char* b_c = (const char*)(w2t + (size_t)e * DDIM * HDIM);
  const int rc0 = (rA0 < mrem) ? rA0 : (mrem - 1);
  const int rc1 = (rA1 < mrem) ? rA1 : (mrem - 1);
  const size_t khb = (size_t)kh * (2048 * 2);   // byte offset of K-half
  const char* ap0 = a_c + (size_t)(off0 + m0 + rc0) * (HDIM * 2) + khb
                        + (((lane & 3) ^ ((rA0 >> 1) & 3)) << 4);
  const char* ap1 = a_c + (size_t)(off0 + m0 + rc1) * (HDIM * 2) + khb
                        + (((lane & 3) ^ ((rA1 >> 1) & 3)) << 4);
  const char* bp0 = b_c + (size_t)(n0 + rA0) * (HDIM * 2) + khb
                        + (((lane & 3) ^ ((rA0 >> 1) & 3)) << 4);
  const char* bp1 = b_c + (size_t)(n0 + rA1) * (HDIM * 2) + khb
                        + (((lane & 3) ^ ((rA1 >> 1) & 3)) << 4);
  char* ldsA = smem;
  char* ldsB = smem + 24576;
  const int ch0 = (wv * 2 + 0) * 1024, ch1 = (wv * 2 + 1) * 1024;

  const unsigned foff = (unsigned)(((lane >> 4) ^ ((l15 >> 1) & 3)) << 4);

  f32x4 acc[4][4] = {};
  const int NT = 2048 / BKK;   // 64

  gload16(ap0, ldsA + ch0);        gload16(ap1, ldsA + ch1);
  gload16(bp0, ldsB + ch0);        gload16(bp1, ldsB + ch1);
  gload16(ap0 + 64, ldsA + 8192 + ch0); gload16(ap1 + 64, ldsA + 8192 + ch1);
  gload16(bp0 + 64, ldsB + 8192 + ch0); gload16(bp1 + 64, ldsB + 8192 + ch1);

  int cur = 0, nx2 = 2;
  for (int ks = 0; ks < NT; ++ks) {
    if (ks + 2 < NT) {
      const size_t kb = (size_t)(ks + 2) * 64;
      const int nb = nx2 * 8192;
      gload16(ap0 + kb, ldsA + nb + ch0); gload16(ap1 + kb, ldsA + nb + ch1);
      gload16(bp0 + kb, ldsB + nb + ch0); gload16(bp1 + kb, ldsB + nb + ch1);
      asm volatile("s_waitcnt vmcnt(8)" ::: "memory");
    } else if (ks + 1 < NT) {
      asm volatile("s_waitcnt vmcnt(4)" ::: "memory");
    } else {
      asm volatile("s_waitcnt vmcnt(0)" ::: "memory");
    }
    __builtin_amdgcn_sched_barrier(0);
    __builtin_amdgcn_s_barrier();
    const char* Ab = ldsA + cur * 8192;
    const char* Bb = ldsB + cur * 8192;
    f16x8 af[4], bfr[4];
#pragma unroll
    for (int m = 0; m < 4; ++m)
      af[m] = *(const f16x8*)(Ab + (wr * 64 + m * 16 + l15) * 64 + foff);
#pragma unroll
    for (int n = 0; n < 4; ++n)
      bfr[n] = *(const f16x8*)(Bb + (wc * 64 + n * 16 + l15) * 64 + foff);
#pragma unroll
    for (int m = 0; m < 4; ++m)
#pragma unroll
      for (int n = 0; n < 4; ++n)
        acc[m][n] = __builtin_amdgcn_mfma_f32_16x16x32_f16(af[m], bfr[n], acc[m][n], 0, 0, 0);
    __builtin_amdgcn_sched_barrier(0);
    __builtin_amdgcn_s_barrier();
    cur = (cur == 2) ? 0 : cur + 1;
    nx2 = (nx2 == 2) ? 0 : nx2 + 1;
  }

  if (YB) {
    _Float16* ypart = yb + (size_t)kh * NPAIR * DDIM;
#pragma unroll
    for (int m = 0; m < 4; ++m) {
#pragma unroll
      for (int j = 0; j < 4; ++j) {
        int row = wr * 64 + m * 16 + (lane >> 4) * 4 + j;
#pragma unroll
        for (int n = 0; n < 4; ++n) {
          int col = wc * 64 + n * 16 + l15;
          *(_Float16*)(smem + (row << 8) + (((col << 1) ^ ((row & 15) << 4)))) =
              (_Float16)acc[m][n][j];
        }
      }
    }
    __syncthreads();
    const int srow = tid >> 1, half = tid & 1;
    if (srow < mrem) {
      _Float16* yr = ypart + (size_t)(off0 + m0 + srow) * DDIM + n0 + half * 64;
#pragma unroll
      for (int i = 0; i < 8; ++i) {
        f16x8 v = *(const f16x8*)(smem + (srow << 8) + (((half * 128 + i * 16) ^ ((srow & 15) << 4))));
        *(f16x8*)(yr + i * 8) = v;
      }
    }
  } else {
    float bias[4];
#pragma unroll
    for (int n = 0; n < 4; ++n)
      bias[n] = (kh == 0) ? b2[(size_t)e * DDIM + n0 + wc * 64 + n * 16 + l15] : 0.f;
#pragma unroll
    for (int m = 0; m < 4; ++m) {
#pragma unroll
      for (int j = 0; j < 4; ++j) {
        int row = wr * 64 + m * 16 + (lane >> 4) * 4 + j;
        if (row < mrem) {
          int g = off0 + m0 + row;
          float wgt = row_w[g];
          float* op = out + (size_t)row_token[g] * DDIM + n0 + wc * 64 + l15;
#pragma unroll
          for (int n = 0; n < 4; ++n)
            atomicAdd(op + n * 16, wgt * (acc[m][n][j] + bias[n]));
        }
      }
    }
  }
}

// ---------------- combine: out[t] = sum_k tw[t,k] * (y0[g]+y1[g] + b2[e_k]) ----------------
__global__ __launch_bounds__(256) void k_combine(const _Float16* __restrict__ yb,
    const int* __restrict__ inv, const int* __restrict__ tidx,
    const float* __restrict__ tw, const float* __restrict__ b2,
    float* __restrict__ out) {
  const int t  = blockIdx.x * 2 + (threadIdx.x >> 7);
  const int c8 = (threadIdx.x & 127) * 8;
  const int g0 = inv[2 * t],  g1 = inv[2 * t + 1];
  const int e0 = tidx[2 * t], e1 = tidx[2 * t + 1];
  const float w0 = tw[2 * t], w1 = tw[2 * t + 1];
  const _Float16* y1p = yb + (size_t)NPAIR * DDIM;
  f16x8 a0 = *(const f16x8*)(yb  + (size_t)g0 * DDIM + c8);
  f16x8 a1 = *(const f16x8*)(y1p + (size_t)g0 * DDIM + c8);
  f16x8 b0 = *(const f16x8*)(yb  + (size_t)g1 * DDIM + c8);
  f16x8 b1v = *(const f16x8*)(y1p + (size_t)g1 * DDIM + c8);
  float o[8];
#pragma unroll
  for (int i = 0; i < 8; ++i) {
    float bA = b2[(size_t)e0 * DDIM + c8 + i];
    float bB = b2[(size_t)e1 * DDIM + c8 + i];
    o[i] = w0 * ((float)a0[i] + (float)a1[i] + bA) + w1 * ((float)b0[i] + (float)b1v[i] + bB);
  }
  float* op = out + (size_t)t * DDIM + c8;
  *(float4*)op       = make_float4(o[0], o[1], o[2], o[3]);
  *(float4*)(op + 4) = make_float4(o[4], o[5], o[6], o[7]);
}

// ---------------- host ----------------
extern "C" void kernel_launch(void* const* d_in, const int* in_sizes, int n_in,
                              void* d_out, int out_size, void* d_ws, size_t ws_size,
                              hipStream_t stream) {
  const float* x  = (const float*)d_in[0];
  const float* rw = (const float*)d_in[1];
  const float* rb = (const float*)d_in[2];
  const float* w1 = (const float*)d_in[3];
  const float* b1 = (const float*)d_in[4];
  const float* w2 = (const float*)d_in[5];
  const float* b2 = (const float*)d_in[6];
  float* out = (float*)d_out;
  char* ws = (char*)d_ws;

  int*      tidx    = (int*)(ws + 0);               // 32KB
  float*    tw      = (float*)(ws + 32768);         // 32KB
  int*      counts  = (int*)(ws + 65536);
  int*      offs    = (int*)(ws + 65792);
  int*      row_tok = (int*)(ws + 66048);           // 32KB
  float*    row_w   = (float*)(ws + 98816);         // 32KB
  int*      inv     = (int*)(ws + 131584);          // 32KB
  _Float16* xb      = (_Float16*)(ws + 164352);     // 8MB
  _Float16* wt      = (_Float16*)(ws + 8552960);    // 64MB (w1t then w2t)
  _Float16* hb      = (_Float16*)(ws + 75661824);   // 64MB
  _Float16* yb      = (_Float16*)(ws + 142770688);  // 32MB (2 x 16MB partials)
  const bool big = ws_size >= 209879552ULL;

  hipMemsetAsync(counts, 0, NEXP * sizeof(int), stream);
  if (!big) hipMemsetAsync(out, 0, (size_t)TOK * DDIM * sizeof(float), stream);

  k_router<<<dim3(TOK / 4), 256, 0, stream>>>(x, rw, rb, tidx, tw, counts, xb);
  k_scan<<<dim3(1), 1024, 0, stream>>>(tidx, tw, counts, offs, row_tok, row_w, inv);
  k_transpose<<<dim3(HDIM / 64, DDIM / 64, NEXP), 256, 0, stream>>>(w1, wt, DDIM, HDIM);
  k_gemm1<<<dim3((HDIM / BN) * (TOK / BM) * NEXP), 256, 0, stream>>>(xb, wt, b1, offs, row_tok, hb);
  k_transpose<<<dim3(DDIM / 64, HDIM / 64, NEXP), 256, 0, stream>>>(w2, wt, HDIM, DDIM);
  if (big) {
    k_gemm2<true><<<dim3((DDIM / BN) * (TOK / BM) * NEXP * 2), 256, 0, stream>>>(
        hb, wt, b2, offs, row_tok, row_w, yb, out);
    k_combine<<<dim3(TOK / 2), 256, 0, stream>>>(yb, inv, tidx, tw, b2, out);
  } else {
    k_gemm2<false><<<dim3((DDIM / BN) * (TOK / BM) * NEXP * 2), 256, 0, stream>>>(
        hb, wt, b2, offs, row_tok, row_w, yb, out);
  }
}

// Round 6
// 425.087 us; speedup vs baseline: 1.9839x; 1.9839x over previous
//
#include <hip/hip_runtime.h>
#include <hip/hip_bf16.h>

#define TOK   4096            // B*S
#define DDIM  1024
#define NEXP  8
#define HDIM  4096
#define KSEL  2
#define NPAIR (TOK * KSEL)    // 8192

typedef __attribute__((ext_vector_type(8))) _Float16 f16x8;
typedef __attribute__((ext_vector_type(4))) _Float16 f16x4;
typedef __attribute__((ext_vector_type(4))) float    f32x4;

__device__ __forceinline__ void gload16(const void* g, void* l) {
  __builtin_amdgcn_global_load_lds((const __attribute__((address_space(1))) void*)g,
                                   (__attribute__((address_space(3))) void*)l, 16, 0, 0);
}

__device__ __forceinline__ float gelu_tanh(float u) {
  float inner = 0.7978845608028654f * (u + 0.044715f * u * u * u);
  float t2 = __expf(2.f * inner);
  return u - u / (t2 + 1.f);     // == 0.5*u*(1+tanh(inner)), overflow-safe
}

// ---------------- router (+ fused x->fp16): one wave per token ----------------
__global__ __launch_bounds__(256) void k_router(const float* __restrict__ x,
    const float* __restrict__ rw, const float* __restrict__ rb,
    int* __restrict__ tidx, float* __restrict__ tw, int* __restrict__ counts,
    _Float16* __restrict__ xb) {
  const int t    = blockIdx.x * 4 + (threadIdx.x >> 6);
  const int lane = threadIdx.x & 63;
  const float* xr = x + (size_t)t * DDIM;
  _Float16*   xbr = xb + (size_t)t * DDIM;
  float acc[NEXP];
#pragma unroll
  for (int e = 0; e < NEXP; ++e) acc[e] = 0.f;
  for (int d0 = lane * 4; d0 < DDIM; d0 += 256) {
    const float4 xv = *(const float4*)(xr + d0);
    f16x4 hx;
    hx[0] = (_Float16)xv.x; hx[1] = (_Float16)xv.y;
    hx[2] = (_Float16)xv.z; hx[3] = (_Float16)xv.w;
    *(f16x4*)(xbr + d0) = hx;
#pragma unroll
    for (int i = 0; i < 4; ++i) {
      const float xs = (&xv.x)[i];
      const float4 r0 = *(const float4*)(rw + (size_t)(d0 + i) * NEXP);
      const float4 r1 = *(const float4*)(rw + (size_t)(d0 + i) * NEXP + 4);
      acc[0] += xs * r0.x; acc[1] += xs * r0.y; acc[2] += xs * r0.z; acc[3] += xs * r0.w;
      acc[4] += xs * r1.x; acc[5] += xs * r1.y; acc[6] += xs * r1.z; acc[7] += xs * r1.w;
    }
  }
#pragma unroll
  for (int e = 0; e < NEXP; ++e) {
    float v = acc[e];
#pragma unroll
    for (int s = 32; s; s >>= 1) v += __shfl_xor(v, s, 64);
    acc[e] = v;
  }
  if (lane == 0) {
    float lg[NEXP];
#pragma unroll
    for (int e = 0; e < NEXP; ++e) lg[e] = acc[e] + rb[e];
    int i0 = 0;
#pragma unroll
    for (int e = 1; e < NEXP; ++e) if (lg[e] > lg[i0]) i0 = e;
    int i1 = -1; float best = -3.4e38f;
#pragma unroll
    for (int e = 0; e < NEXP; ++e) {
      if (e == i0) continue;
      if (lg[e] > best) { best = lg[e]; i1 = e; }
    }
    float w0 = 1.f / (1.f + expf(lg[i1] - lg[i0]));
    tidx[t * 2]     = i0;  tidx[t * 2 + 1] = i1;
    tw[t * 2]       = w0;  tw[t * 2 + 1]   = 1.f - w0;
    atomicAdd(&counts[i0], 1);
    atomicAdd(&counts[i1], 1);
  }
}

// ---------------- scan + scatter (single block, ballot-aggregated) ----------------
__global__ __launch_bounds__(1024) void k_scan(const int* __restrict__ tidx,
                       const float* __restrict__ tw,
                       const int* __restrict__ counts, int* __restrict__ offs,
                       int* __restrict__ row_token, float* __restrict__ row_w,
                       int* __restrict__ inv) {
  __shared__ int soff[NEXP + 1];
  __shared__ int scur[NEXP];
  if (threadIdx.x == 0) {
    int run = 0;
    for (int e = 0; e < NEXP; ++e) { soff[e] = run; run += counts[e]; }
    soff[NEXP] = run;
    for (int e = 0; e <= NEXP; ++e) offs[e] = soff[e];
  }
  __syncthreads();
  if (threadIdx.x < NEXP) scur[threadIdx.x] = soff[threadIdx.x];
  __syncthreads();
  const int lane = threadIdx.x & 63;
#pragma unroll
  for (int it = 0; it < NPAIR / 1024; ++it) {
    const int p = it * 1024 + threadIdx.x;
    const int e = tidx[p];
    int pos = 0;
#pragma unroll
    for (int ee = 0; ee < NEXP; ++ee) {
      unsigned long long m = __ballot(e == ee);
      if (!m) continue;
      int base = 0;
      if (lane == 0) base = atomicAdd(&scur[ee], __popcll(m));
      base = __shfl(base, 0, 64);
      if (e == ee) pos = base + __popcll(m & ((1ull << lane) - 1ull));
    }
    row_token[pos] = p >> 1;
    row_w[pos]     = tw[p];
    inv[p]         = pos;
  }
}

// ---------------- transpose fp32 [Rr][Cc] -> fp16 [Cc][Rr], per expert ----------------
__global__ __launch_bounds__(256) void k_transpose(const float* __restrict__ in,
    _Float16* __restrict__ out, int Rr, int Cc) {
  __shared__ _Float16 tile[64][72];
  const size_t esz = (size_t)Rr * Cc;
  const float* ip = in + esz * blockIdx.z;
  _Float16*    op = out + esz * blockIdx.z;
  const int i0 = blockIdx.y * 64;
  const int j0 = blockIdx.x * 64;
  const int tx = threadIdx.x & 15, ty = threadIdx.x >> 4;
#pragma unroll
  for (int rr = 0; rr < 4; ++rr) {
    int r = ty + rr * 16;
    float4 v = *(const float4*)(ip + (size_t)(i0 + r) * Cc + j0 + tx * 4);
    tile[r][tx * 4 + 0] = (_Float16)v.x;
    tile[r][tx * 4 + 1] = (_Float16)v.y;
    tile[r][tx * 4 + 2] = (_Float16)v.z;
    tile[r][tx * 4 + 3] = (_Float16)v.w;
  }
  __syncthreads();
#pragma unroll
  for (int cc = 0; cc < 4; ++cc) {
    int c = ty + cc * 16;
    f16x4 o;
#pragma unroll
    for (int k = 0; k < 4; ++k) o[k] = tile[tx * 4 + k][c];
    *(f16x4*)(op + (size_t)(j0 + c) * Rr + i0 + tx * 4) = o;
  }
}

#define BM 128
#define BN 128
#define BKK 32

// LDS: A[3 bufs x 8K] at 0, B[3 bufs x 8K] at 24K -> 48KB (3 blocks/CU).
// Rows of 64B = 4 slots of 16B; physical slot = logical ^ ((row>>1)&3).
// Pipeline: loads for tile ks+2 issued at iter ks; vmcnt(8) waits only tile ks
// (2 iterations of lead, ~2x the HBM latency). Grid is 3D, x (N-tile) fastest:
// active blocks stay contiguous in dispatch order -> spread over all CUs.
// (r5 lesson: low-bits-sparse 1D remap serialized the machine 3.3x.)

// ---------------- GEMM1: h = gelu(X_gathered @ w1t^T + b1), fp16 out ----------------
__global__ __launch_bounds__(256) void k_gemm1(
    const _Float16* __restrict__ xb,    // [TOK][DDIM]
    const _Float16* __restrict__ w1t,   // [NEXP][HDIM][DDIM]
    const float* __restrict__ b1,       // [NEXP][HDIM]
    const int* __restrict__ offs,
    const int* __restrict__ row_token,
    _Float16* __restrict__ hbuf) {      // [NPAIR][HDIM]
  const int e  = blockIdx.z;
  const int off0 = offs[e];
  const int ne   = offs[e + 1] - off0;
  const int m0   = blockIdx.y * BM;
  if (m0 >= ne) return;
  const int n0   = blockIdx.x * BN;
  const int mrem = ne - m0;

  __shared__ __align__(16) char smem[49152];

  const int tid = threadIdx.x;
  const int wv = tid >> 6, lane = tid & 63;
  const int l15 = lane & 15;
  const int wr = wv >> 1, wc = wv & 1;

  const int rA0 = (wv * 2 + 0) * 16 + (lane >> 2);
  const int rA1 = (wv * 2 + 1) * 16 + (lane >> 2);
  const char* a_c = (const char*)xb;
  const char* b_c = (const char*)(w1t + (size_t)e * HDIM * DDIM);
  const int rc0 = (rA0 < mrem) ? rA0 : (mrem - 1);
  const int rc1 = (rA1 < mrem) ? rA1 : (mrem - 1);
  const char* ap0 = a_c + (size_t)row_token[off0 + m0 + rc0] * (DDIM * 2)
                        + (((lane & 3) ^ ((rA0 >> 1) & 3)) << 4);
  const char* ap1 = a_c + (size_t)row_token[off0 + m0 + rc1] * (DDIM * 2)
                        + (((lane & 3) ^ ((rA1 >> 1) & 3)) << 4);
  const char* bp0 = b_c + (size_t)(n0 + rA0) * (DDIM * 2)
                        + (((lane & 3) ^ ((rA0 >> 1) & 3)) << 4);
  const char* bp1 = b_c + (size_t)(n0 + rA1) * (DDIM * 2)
                        + (((lane & 3) ^ ((rA1 >> 1) & 3)) << 4);
  char* ldsA = smem;
  char* ldsB = smem + 24576;
  const int ch0 = (wv * 2 + 0) * 1024, ch1 = (wv * 2 + 1) * 1024;

  const unsigned foff = (unsigned)(((lane >> 4) ^ ((l15 >> 1) & 3)) << 4);

  f32x4 acc[4][4] = {};
  const int NT = DDIM / BKK;   // 32

  // prologue: stage ks=0 -> buf0, ks=1 -> buf1
  gload16(ap0, ldsA + ch0);        gload16(ap1, ldsA + ch1);
  gload16(bp0, ldsB + ch0);        gload16(bp1, ldsB + ch1);
  gload16(ap0 + 64, ldsA + 8192 + ch0); gload16(ap1 + 64, ldsA + 8192 + ch1);
  gload16(bp0 + 64, ldsB + 8192 + ch0); gload16(bp1 + 64, ldsB + 8192 + ch1);

  int cur = 0, nx2 = 2;
#pragma unroll 3
  for (int ks = 0; ks < NT; ++ks) {
    if (ks + 2 < NT) {
      const size_t kb = (size_t)(ks + 2) * 64;
      const int nb = nx2 * 8192;
      gload16(ap0 + kb, ldsA + nb + ch0); gload16(ap1 + kb, ldsA + nb + ch1);
      gload16(bp0 + kb, ldsB + nb + ch0); gload16(bp1 + kb, ldsB + nb + ch1);
      asm volatile("s_waitcnt vmcnt(8)" ::: "memory");
    } else if (ks + 1 < NT) {
      asm volatile("s_waitcnt vmcnt(4)" ::: "memory");
    } else {
      asm volatile("s_waitcnt vmcnt(0)" ::: "memory");
    }
    __builtin_amdgcn_sched_barrier(0);
    __builtin_amdgcn_s_barrier();
    const char* Ab = ldsA + cur * 8192;
    const char* Bb = ldsB + cur * 8192;
    f16x8 af[4], bfr[4];
#pragma unroll
    for (int m = 0; m < 4; ++m)
      af[m] = *(const f16x8*)(Ab + (wr * 64 + m * 16 + l15) * 64 + foff);
#pragma unroll
    for (int n = 0; n < 4; ++n)
      bfr[n] = *(const f16x8*)(Bb + (wc * 64 + n * 16 + l15) * 64 + foff);
#pragma unroll
    for (int m = 0; m < 4; ++m)
#pragma unroll
      for (int n = 0; n < 4; ++n)
        acc[m][n] = __builtin_amdgcn_mfma_f32_16x16x32_f16(af[m], bfr[n], acc[m][n], 0, 0, 0);
    __builtin_amdgcn_sched_barrier(0);
    __builtin_amdgcn_s_barrier();
    cur = (cur == 2) ? 0 : cur + 1;
    nx2 = (nx2 == 2) ? 0 : nx2 + 1;
  }

  // epilogue: bias + gelu -> restage f16 C-tile in LDS -> coalesced stores
  float bias[4];
#pragma unroll
  for (int n = 0; n < 4; ++n)
    bias[n] = b1[(size_t)e * HDIM + n0 + wc * 64 + n * 16 + l15];
#pragma unroll
  for (int m = 0; m < 4; ++m) {
#pragma unroll
    for (int j = 0; j < 4; ++j) {
      int row = wr * 64 + m * 16 + (lane >> 4) * 4 + j;
#pragma unroll
      for (int n = 0; n < 4; ++n) {
        int col = wc * 64 + n * 16 + l15;
        *(_Float16*)(smem + (row << 8) + (((col << 1) ^ ((row & 15) << 4)))) =
            (_Float16)gelu_tanh(acc[m][n][j] + bias[n]);
      }
    }
  }
  __syncthreads();
  {
    const int srow = tid >> 1, half = tid & 1;
    if (srow < mrem) {
      _Float16* hr = hbuf + (size_t)(off0 + m0 + srow) * HDIM + n0 + half * 64;
#pragma unroll
      for (int i = 0; i < 8; ++i) {
        f16x8 v = *(const f16x8*)(smem + (srow << 8) + (((half * 128 + i * 16) ^ ((srow & 15) << 4))));
        *(f16x8*)(hr + i * 8) = v;
      }
    }
  }
}

// ---------------- GEMM2 (split-K=2): ypart[kh] = H @ w2t^T ----------------
template <bool YB>
__global__ __launch_bounds__(256) void k_gemm2(
    const _Float16* __restrict__ hbuf,  // [NPAIR][HDIM]
    const _Float16* __restrict__ w2t,   // [NEXP][DDIM][HDIM]
    const float* __restrict__ b2,       // [NEXP][DDIM]
    const int* __restrict__ offs,
    const int* __restrict__ row_token,
    const float* __restrict__ row_w,
    _Float16* __restrict__ yb,          // [2][NPAIR][DDIM] partials (YB path)
    float* __restrict__ out) {          // [TOK][DDIM]      (atomic path)
  const int zz = blockIdx.z;            // 0..15
  const int e  = zz >> 1;
  const int kh = zz & 1;
  const int off0 = offs[e];
  const int ne   = offs[e + 1] - off0;
  const int m0   = blockIdx.y * BM;
  if (m0 >= ne) return;
  const int n0   = blockIdx.x * BN;
  const int mrem = ne - m0;

  __shared__ __align__(16) char smem[49152];

  const int tid = threadIdx.x;
  const int wv = tid >> 6, lane = tid & 63;
  const int l15 = lane & 15;
  const int wr = wv >> 1, wc = wv & 1;

  const int rA0 = (wv * 2 + 0) * 16 + (lane >> 2);
  const int rA1 = (wv * 2 + 1) * 16 + (lane >> 2);
  const char* a_c = (const char*)hbuf;
  const char* b_c = (const char*)(w2t + (size_t)e * DDIM * HDIM);
  const int rc0 = (rA0 < mrem) ? rA0 : (mrem - 1);
  const int rc1 = (rA1 < mrem) ? rA1 : (mrem - 1);
  const size_t khb = (size_t)kh * (2048 * 2);   // byte offset of K-half
  const char* ap0 = a_c + (size_t)(off0 + m0 + rc0) * (HDIM * 2) + khb
                        + (((lane & 3) ^ ((rA0 >> 1) & 3)) << 4);
  const char* ap1 = a_c + (size_t)(off0 + m0 + rc1) * (HDIM * 2) + khb
                        + (((lane & 3) ^ ((rA1 >> 1) & 3)) << 4);
  const char* bp0 = b_c + (size_t)(n0 + rA0) * (HDIM * 2) + khb
                        + (((lane & 3) ^ ((rA0 >> 1) & 3)) << 4);
  const char* bp1 = b_c + (size_t)(n0 + rA1) * (HDIM * 2) + khb
                        + (((lane & 3) ^ ((rA1 >> 1) & 3)) << 4);
  char* ldsA = smem;
  char* ldsB = smem + 24576;
  const int ch0 = (wv * 2 + 0) * 1024, ch1 = (wv * 2 + 1) * 1024;

  const unsigned foff = (unsigned)(((lane >> 4) ^ ((l15 >> 1) & 3)) << 4);

  f32x4 acc[4][4] = {};
  const int NT = 2048 / BKK;   // 64

  gload16(ap0, ldsA + ch0);        gload16(ap1, ldsA + ch1);
  gload16(bp0, ldsB + ch0);        gload16(bp1, ldsB + ch1);
  gload16(ap0 + 64, ldsA + 8192 + ch0); gload16(ap1 + 64, ldsA + 8192 + ch1);
  gload16(bp0 + 64, ldsB + 8192 + ch0); gload16(bp1 + 64, ldsB + 8192 + ch1);

  int cur = 0, nx2 = 2;
#pragma unroll 3
  for (int ks = 0; ks < NT; ++ks) {
    if (ks + 2 < NT) {
      const size_t kb = (size_t)(ks + 2) * 64;
      const int nb = nx2 * 8192;
      gload16(ap0 + kb, ldsA + nb + ch0); gload16(ap1 + kb, ldsA + nb + ch1);
      gload16(bp0 + kb, ldsB + nb + ch0); gload16(bp1 + kb, ldsB + nb + ch1);
      asm volatile("s_waitcnt vmcnt(8)" ::: "memory");
    } else if (ks + 1 < NT) {
      asm volatile("s_waitcnt vmcnt(4)" ::: "memory");
    } else {
      asm volatile("s_waitcnt vmcnt(0)" ::: "memory");
    }
    __builtin_amdgcn_sched_barrier(0);
    __builtin_amdgcn_s_barrier();
    const char* Ab = ldsA + cur * 8192;
    const char* Bb = ldsB + cur * 8192;
    f16x8 af[4], bfr[4];
#pragma unroll
    for (int m = 0; m < 4; ++m)
      af[m] = *(const f16x8*)(Ab + (wr * 64 + m * 16 + l15) * 64 + foff);
#pragma unroll
    for (int n = 0; n < 4; ++n)
      bfr[n] = *(const f16x8*)(Bb + (wc * 64 + n * 16 + l15) * 64 + foff);
#pragma unroll
    for (int m = 0; m < 4; ++m)
#pragma unroll
      for (int n = 0; n < 4; ++n)
        acc[m][n] = __builtin_amdgcn_mfma_f32_16x16x32_f16(af[m], bfr[n], acc[m][n], 0, 0, 0);
    __builtin_amdgcn_sched_barrier(0);
    __builtin_amdgcn_s_barrier();
    cur = (cur == 2) ? 0 : cur + 1;
    nx2 = (nx2 == 2) ? 0 : nx2 + 1;
  }

  if (YB) {
    _Float16* ypart = yb + (size_t)kh * NPAIR * DDIM;
#pragma unroll
    for (int m = 0; m < 4; ++m) {
#pragma unroll
      for (int j = 0; j < 4; ++j) {
        int row = wr * 64 + m * 16 + (lane >> 4) * 4 + j;
#pragma unroll
        for (int n = 0; n < 4; ++n) {
          int col = wc * 64 + n * 16 + l15;
          *(_Float16*)(smem + (row << 8) + (((col << 1) ^ ((row & 15) << 4)))) =
              (_Float16)acc[m][n][j];
        }
      }
    }
    __syncthreads();
    const int srow = tid >> 1, half = tid & 1;
    if (srow < mrem) {
      _Float16* yr = ypart + (size_t)(off0 + m0 + srow) * DDIM + n0 + half * 64;
#pragma unroll
      for (int i = 0; i < 8; ++i) {
        f16x8 v = *(const f16x8*)(smem + (srow << 8) + (((half * 128 + i * 16) ^ ((srow & 15) << 4))));
        *(f16x8*)(yr + i * 8) = v;
      }
    }
  } else {
    float bias[4];
#pragma unroll
    for (int n = 0; n < 4; ++n)
      bias[n] = (kh == 0) ? b2[(size_t)e * DDIM + n0 + wc * 64 + n * 16 + l15] : 0.f;
#pragma unroll
    for (int m = 0; m < 4; ++m) {
#pragma unroll
      for (int j = 0; j < 4; ++j) {
        int row = wr * 64 + m * 16 + (lane >> 4) * 4 + j;
        if (row < mrem) {
          int g = off0 + m0 + row;
          float wgt = row_w[g];
          float* op = out + (size_t)row_token[g] * DDIM + n0 + wc * 64 + l15;
#pragma unroll
          for (int n = 0; n < 4; ++n)
            atomicAdd(op + n * 16, wgt * (acc[m][n][j] + bias[n]));
        }
      }
    }
  }
}

// ---------------- combine: out[t] = sum_k tw[t,k] * (y0[g]+y1[g] + b2[e_k]) ----------------
__global__ __launch_bounds__(256) void k_combine(const _Float16* __restrict__ yb,
    const int* __restrict__ inv, const int* __restrict__ tidx,
    const float* __restrict__ tw, const float* __restrict__ b2,
    float* __restrict__ out) {
  const int t  = blockIdx.x * 2 + (threadIdx.x >> 7);
  const int c8 = (threadIdx.x & 127) * 8;
  const int g0 = inv[2 * t],  g1 = inv[2 * t + 1];
  const int e0 = tidx[2 * t], e1 = tidx[2 * t + 1];
  const float w0 = tw[2 * t], w1 = tw[2 * t + 1];
  const _Float16* y1p = yb + (size_t)NPAIR * DDIM;
  f16x8 a0 = *(const f16x8*)(yb  + (size_t)g0 * DDIM + c8);
  f16x8 a1 = *(const f16x8*)(y1p + (size_t)g0 * DDIM + c8);
  f16x8 b0 = *(const f16x8*)(yb  + (size_t)g1 * DDIM + c8);
  f16x8 b1v = *(const f16x8*)(y1p + (size_t)g1 * DDIM + c8);
  float o[8];
#pragma unroll
  for (int i = 0; i < 8; ++i) {
    float bA = b2[(size_t)e0 * DDIM + c8 + i];
    float bB = b2[(size_t)e1 * DDIM + c8 + i];
    o[i] = w0 * ((float)a0[i] + (float)a1[i] + bA) + w1 * ((float)b0[i] + (float)b1v[i] + bB);
  }
  float* op = out + (size_t)t * DDIM + c8;
  *(float4*)op       = make_float4(o[0], o[1], o[2], o[3]);
  *(float4*)(op + 4) = make_float4(o[4], o[5], o[6], o[7]);
}

// ---------------- host ----------------
extern "C" void kernel_launch(void* const* d_in, const int* in_sizes, int n_in,
                              void* d_out, int out_size, void* d_ws, size_t ws_size,
                              hipStream_t stream) {
  const float* x  = (const float*)d_in[0];
  const float* rw = (const float*)d_in[1];
  const float* rb = (const float*)d_in[2];
  const float* w1 = (const float*)d_in[3];
  const float* b1 = (const float*)d_in[4];
  const float* w2 = (const float*)d_in[5];
  const float* b2 = (const float*)d_in[6];
  float* out = (float*)d_out;
  char* ws = (char*)d_ws;

  int*      tidx    = (int*)(ws + 0);               // 32KB
  float*    tw      = (float*)(ws + 32768);         // 32KB
  int*      counts  = (int*)(ws + 65536);
  int*      offs    = (int*)(ws + 65792);
  int*      row_tok = (int*)(ws + 66048);           // 32KB
  float*    row_w   = (float*)(ws + 98816);         // 32KB
  int*      inv     = (int*)(ws + 131584);          // 32KB
  _Float16* xb      = (_Float16*)(ws + 164352);     // 8MB
  _Float16* wt      = (_Float16*)(ws + 8552960);    // 64MB (w1t then w2t)
  _Float16* hb      = (_Float16*)(ws + 75661824);   // 64MB
  _Float16* yb      = (_Float16*)(ws + 142770688);  // 32MB (2 x 16MB partials)
  const bool big = ws_size >= 209879552ULL;

  hipMemsetAsync(counts, 0, NEXP * sizeof(int), stream);
  if (!big) hipMemsetAsync(out, 0, (size_t)TOK * DDIM * sizeof(float), stream);

  k_router<<<dim3(TOK / 4), 256, 0, stream>>>(x, rw, rb, tidx, tw, counts, xb);
  k_scan<<<dim3(1), 1024, 0, stream>>>(tidx, tw, counts, offs, row_tok, row_w, inv);
  k_transpose<<<dim3(HDIM / 64, DDIM / 64, NEXP), 256, 0, stream>>>(w1, wt, DDIM, HDIM);
  k_gemm1<<<dim3(HDIM / BN, TOK / BM, NEXP), 256, 0, stream>>>(xb, wt, b1, offs, row_tok, hb);
  k_transpose<<<dim3(DDIM / 64, HDIM / 64, NEXP), 256, 0, stream>>>(w2, wt, HDIM, DDIM);
  if (big) {
    k_gemm2<true><<<dim3(DDIM / BN, TOK / BM, NEXP * 2), 256, 0, stream>>>(
        hb, wt, b2, offs, row_tok, row_w, yb, out);
    k_combine<<<dim3(TOK / 2), 256, 0, stream>>>(yb, inv, tidx, tw, b2, out);
  } else {
    k_gemm2<false><<<dim3(DDIM / BN, TOK / BM, NEXP * 2), 256, 0, stream>>>(
        hb, wt, b2, offs, row_tok, row_w, yb, out);
  }
}

// Round 7
// 352.051 us; speedup vs baseline: 2.3955x; 1.2075x over previous
//
#include <hip/hip_runtime.h>
#include <hip/hip_bf16.h>

#define TOK   4096            // B*S
#define DDIM  1024
#define NEXP  8
#define HDIM  4096
#define KSEL  2
#define NPAIR (TOK * KSEL)    // 8192
#define NSPLIT 4              // gemm2 split-K factor

typedef __attribute__((ext_vector_type(8))) _Float16 f16x8;
typedef __attribute__((ext_vector_type(4))) _Float16 f16x4;
typedef __attribute__((ext_vector_type(4))) float    f32x4;

__device__ __forceinline__ void gload16(const void* g, void* l) {
  __builtin_amdgcn_global_load_lds((const __attribute__((address_space(1))) void*)g,
                                   (__attribute__((address_space(3))) void*)l, 16, 0, 0);
}

__device__ __forceinline__ float gelu_tanh(float u) {
  float inner = 0.7978845608028654f * (u + 0.044715f * u * u * u);
  float t2 = __expf(2.f * inner);
  return u - u / (t2 + 1.f);     // == 0.5*u*(1+tanh(inner)), overflow-safe
}

// ---------------- router (+ fused x->fp16): one wave per token ----------------
__global__ __launch_bounds__(256) void k_router(const float* __restrict__ x,
    const float* __restrict__ rw, const float* __restrict__ rb,
    int* __restrict__ tidx, float* __restrict__ tw,
    _Float16* __restrict__ xb) {
  const int t    = blockIdx.x * 4 + (threadIdx.x >> 6);
  const int lane = threadIdx.x & 63;
  const float* xr = x + (size_t)t * DDIM;
  _Float16*   xbr = xb + (size_t)t * DDIM;
  float acc[NEXP];
#pragma unroll
  for (int e = 0; e < NEXP; ++e) acc[e] = 0.f;
  for (int d0 = lane * 4; d0 < DDIM; d0 += 256) {
    const float4 xv = *(const float4*)(xr + d0);
    f16x4 hx;
    hx[0] = (_Float16)xv.x; hx[1] = (_Float16)xv.y;
    hx[2] = (_Float16)xv.z; hx[3] = (_Float16)xv.w;
    *(f16x4*)(xbr + d0) = hx;
#pragma unroll
    for (int i = 0; i < 4; ++i) {
      const float xs = (&xv.x)[i];
      const float4 r0 = *(const float4*)(rw + (size_t)(d0 + i) * NEXP);
      const float4 r1 = *(const float4*)(rw + (size_t)(d0 + i) * NEXP + 4);
      acc[0] += xs * r0.x; acc[1] += xs * r0.y; acc[2] += xs * r0.z; acc[3] += xs * r0.w;
      acc[4] += xs * r1.x; acc[5] += xs * r1.y; acc[6] += xs * r1.z; acc[7] += xs * r1.w;
    }
  }
#pragma unroll
  for (int e = 0; e < NEXP; ++e) {
    float v = acc[e];
#pragma unroll
    for (int s = 32; s; s >>= 1) v += __shfl_xor(v, s, 64);
    acc[e] = v;
  }
  if (lane == 0) {
    float lg[NEXP];
#pragma unroll
    for (int e = 0; e < NEXP; ++e) lg[e] = acc[e] + rb[e];
    int i0 = 0;
#pragma unroll
    for (int e = 1; e < NEXP; ++e) if (lg[e] > lg[i0]) i0 = e;
    int i1 = -1; float best = -3.4e38f;
#pragma unroll
    for (int e = 0; e < NEXP; ++e) {
      if (e == i0) continue;
      if (lg[e] > best) { best = lg[e]; i1 = e; }
    }
    float w0 = 1.f / (1.f + expf(lg[i1] - lg[i0]));
    tidx[t * 2]     = i0;  tidx[t * 2 + 1] = i1;
    tw[t * 2]       = w0;  tw[t * 2 + 1]   = 1.f - w0;
  }
}

// ---------------- scan: histogram + prefix + scatter (single block) ----------------
__global__ __launch_bounds__(1024) void k_scan(const int* __restrict__ tidx,
                       const float* __restrict__ tw,
                       int* __restrict__ offs,
                       int* __restrict__ row_token, float* __restrict__ row_w,
                       int* __restrict__ inv) {
  __shared__ int hist[NEXP];
  __shared__ int soff[NEXP + 1];
  __shared__ int scur[NEXP];
  if (threadIdx.x < NEXP) hist[threadIdx.x] = 0;
  __syncthreads();
  const int lane = threadIdx.x & 63;
  int e_loc[NPAIR / 1024];
#pragma unroll
  for (int it = 0; it < NPAIR / 1024; ++it) {
    const int p = it * 1024 + threadIdx.x;
    const int e = tidx[p];
    e_loc[it] = e;
#pragma unroll
    for (int ee = 0; ee < NEXP; ++ee) {
      unsigned long long m = __ballot(e == ee);
      if (m && lane == 0) atomicAdd(&hist[ee], __popcll(m));
    }
  }
  __syncthreads();
  if (threadIdx.x == 0) {
    int run = 0;
    for (int e = 0; e < NEXP; ++e) { soff[e] = run; scur[e] = run; run += hist[e]; }
    soff[NEXP] = run;
    for (int e = 0; e <= NEXP; ++e) offs[e] = soff[e];
  }
  __syncthreads();
#pragma unroll
  for (int it = 0; it < NPAIR / 1024; ++it) {
    const int p = it * 1024 + threadIdx.x;
    const int e = e_loc[it];
    int pos = 0;
#pragma unroll
    for (int ee = 0; ee < NEXP; ++ee) {
      unsigned long long m = __ballot(e == ee);
      if (!m) continue;
      int base = 0;
      if (lane == 0) base = atomicAdd(&scur[ee], __popcll(m));
      base = __shfl(base, 0, 64);
      if (e == ee) pos = base + __popcll(m & ((1ull << lane) - 1ull));
    }
    row_token[pos] = p >> 1;
    row_w[pos]     = tw[p];
    inv[p]         = pos;
  }
}

// ---------------- transpose fp32 [Rr][Cc] -> fp16 [Cc][Rr], per expert ----------------
__global__ __launch_bounds__(256) void k_transpose(const float* __restrict__ in,
    _Float16* __restrict__ out, int Rr, int Cc) {
  __shared__ _Float16 tile[64][72];
  const size_t esz = (size_t)Rr * Cc;
  const float* ip = in + esz * blockIdx.z;
  _Float16*    op = out + esz * blockIdx.z;
  const int i0 = blockIdx.y * 64;
  const int j0 = blockIdx.x * 64;
  const int tx = threadIdx.x & 15, ty = threadIdx.x >> 4;
#pragma unroll
  for (int rr = 0; rr < 4; ++rr) {
    int r = ty + rr * 16;
    float4 v = *(const float4*)(ip + (size_t)(i0 + r) * Cc + j0 + tx * 4);
    tile[r][tx * 4 + 0] = (_Float16)v.x;
    tile[r][tx * 4 + 1] = (_Float16)v.y;
    tile[r][tx * 4 + 2] = (_Float16)v.z;
    tile[r][tx * 4 + 3] = (_Float16)v.w;
  }
  __syncthreads();
#pragma unroll
  for (int cc = 0; cc < 4; ++cc) {
    int c = ty + cc * 16;
    f16x4 o;
#pragma unroll
    for (int k = 0; k < 4; ++k) o[k] = tile[tx * 4 + k][c];
    *(f16x4*)(op + (size_t)(j0 + c) * Rr + i0 + tx * 4) = o;
  }
}

#define BM 128
#define BN 128
#define BKK 32

// LDS: A0[8K] A1[8K] B0[8K] B1[8K] = 32KB -> 5 blocks/CU (20 waves/CU; TLP
// hides load latency — r6 proved extra prefetch depth adds nothing).
// Rows of 64B = 4 slots of 16B; physical slot = logical ^ ((row>>1)&3).

// ---------------- GEMM1: h = gelu(X_gathered @ w1t^T + b1), fp16 out ----------------
__global__ __launch_bounds__(256) void k_gemm1(
    const _Float16* __restrict__ xb,    // [TOK][DDIM]
    const _Float16* __restrict__ w1t,   // [NEXP][HDIM][DDIM]
    const float* __restrict__ b1,       // [NEXP][HDIM]
    const int* __restrict__ offs,
    const int* __restrict__ row_token,
    _Float16* __restrict__ hbuf) {      // [NPAIR][HDIM]
  const int e    = blockIdx.z;
  const int off0 = offs[e];
  const int ne   = offs[e + 1] - off0;
  const int m0   = blockIdx.y * BM;
  if (m0 >= ne) return;
  const int n0   = blockIdx.x * BN;
  const int mrem = ne - m0;

  __shared__ __align__(16) char smem[32768];

  const int tid = threadIdx.x;
  const int wv = tid >> 6, lane = tid & 63;
  const int l15 = lane & 15;
  const int wr = wv >> 1, wc = wv & 1;

  const int rA0 = (wv * 2 + 0) * 16 + (lane >> 2);
  const int rA1 = (wv * 2 + 1) * 16 + (lane >> 2);
  const char* a_c = (const char*)xb;
  const char* b_c = (const char*)(w1t + (size_t)e * HDIM * DDIM);
  const int rc0 = (rA0 < mrem) ? rA0 : (mrem - 1);
  const int rc1 = (rA1 < mrem) ? rA1 : (mrem - 1);
  const char* ap0 = a_c + (size_t)row_token[off0 + m0 + rc0] * (DDIM * 2)
                        + (((lane & 3) ^ ((rA0 >> 1) & 3)) << 4);
  const char* ap1 = a_c + (size_t)row_token[off0 + m0 + rc1] * (DDIM * 2)
                        + (((lane & 3) ^ ((rA1 >> 1) & 3)) << 4);
  const char* bp0 = b_c + (size_t)(n0 + rA0) * (DDIM * 2)
                        + (((lane & 3) ^ ((rA0 >> 1) & 3)) << 4);
  const char* bp1 = b_c + (size_t)(n0 + rA1) * (DDIM * 2)
                        + (((lane & 3) ^ ((rA1 >> 1) & 3)) << 4);
  char* ldsA0 = smem + (wv * 2 + 0) * 1024;
  char* ldsA1 = smem + (wv * 2 + 1) * 1024;
  char* ldsB0 = smem + 16384 + (wv * 2 + 0) * 1024;
  char* ldsB1 = smem + 16384 + (wv * 2 + 1) * 1024;

  const unsigned foff = (unsigned)(((lane >> 4) ^ ((l15 >> 1) & 3)) << 4);

  f32x4 acc[4][4] = {};
  const int NT = DDIM / BKK;   // 32

  gload16(ap0, ldsA0); gload16(ap1, ldsA1);
  gload16(bp0, ldsB0); gload16(bp1, ldsB1);

#pragma unroll 2
  for (int ks = 0; ks < NT; ++ks) {
    const int cur = ks & 1;
    if (ks + 1 < NT) {
      const int nb = (cur ^ 1) * 8192;
      const size_t kb = (size_t)(ks + 1) * 64;
      gload16(ap0 + kb, ldsA0 + nb); gload16(ap1 + kb, ldsA1 + nb);
      gload16(bp0 + kb, ldsB0 + nb); gload16(bp1 + kb, ldsB1 + nb);
      asm volatile("s_waitcnt vmcnt(4)" ::: "memory");
    } else {
      asm volatile("s_waitcnt vmcnt(0)" ::: "memory");
    }
    __builtin_amdgcn_sched_barrier(0);
    __builtin_amdgcn_s_barrier();
    const char* Ab = smem + cur * 8192;
    const char* Bb = smem + 16384 + cur * 8192;
    f16x8 af[4], bfr[4];
#pragma unroll
    for (int m = 0; m < 4; ++m)
      af[m] = *(const f16x8*)(Ab + (wr * 64 + m * 16 + l15) * 64 + foff);
#pragma unroll
    for (int n = 0; n < 4; ++n)
      bfr[n] = *(const f16x8*)(Bb + (wc * 64 + n * 16 + l15) * 64 + foff);
#pragma unroll
    for (int m = 0; m < 4; ++m)
#pragma unroll
      for (int n = 0; n < 4; ++n)
        acc[m][n] = __builtin_amdgcn_mfma_f32_16x16x32_f16(af[m], bfr[n], acc[m][n], 0, 0, 0);
    __builtin_amdgcn_sched_barrier(0);
    __builtin_amdgcn_s_barrier();
  }

  // epilogue: bias + gelu -> restage f16 C-tile in LDS -> coalesced stores
  float bias[4];
#pragma unroll
  for (int n = 0; n < 4; ++n)
    bias[n] = b1[(size_t)e * HDIM + n0 + wc * 64 + n * 16 + l15];
#pragma unroll
  for (int m = 0; m < 4; ++m) {
#pragma unroll
    for (int j = 0; j < 4; ++j) {
      int row = wr * 64 + m * 16 + (lane >> 4) * 4 + j;
#pragma unroll
      for (int n = 0; n < 4; ++n) {
        int col = wc * 64 + n * 16 + l15;
        *(_Float16*)(smem + (row << 8) + (((col << 1) ^ ((row & 15) << 4)))) =
            (_Float16)gelu_tanh(acc[m][n][j] + bias[n]);
      }
    }
  }
  __syncthreads();
  {
    const int srow = tid >> 1, half = tid & 1;
    if (srow < mrem) {
      _Float16* hr = hbuf + (size_t)(off0 + m0 + srow) * HDIM + n0 + half * 64;
#pragma unroll
      for (int i = 0; i < 8; ++i) {
        f16x8 v = *(const f16x8*)(smem + (srow << 8) + (((half * 128 + i * 16) ^ ((srow & 15) << 4))));
        *(f16x8*)(hr + i * 8) = v;
      }
    }
  }
}

// ---------------- GEMM2 (split-K=4): ypart[kh] = H @ w2t^T ----------------
template <bool YB>
__global__ __launch_bounds__(256) void k_gemm2(
    const _Float16* __restrict__ hbuf,  // [NPAIR][HDIM]
    const _Float16* __restrict__ w2t,   // [NEXP][DDIM][HDIM]
    const float* __restrict__ b2,       // [NEXP][DDIM]
    const int* __restrict__ offs,
    const int* __restrict__ row_token,
    const float* __restrict__ row_w,
    _Float16* __restrict__ yb,          // [NSPLIT][NPAIR][DDIM] partials (YB)
    float* __restrict__ out) {          // [TOK][DDIM] (atomic path)
  const int zz = blockIdx.z;            // 0..31
  const int e  = zz >> 2;
  const int kh = zz & 3;
  const int off0 = offs[e];
  const int ne   = offs[e + 1] - off0;
  const int m0   = blockIdx.y * BM;
  if (m0 >= ne) return;
  const int n0   = blockIdx.x * BN;
  const int mrem = ne - m0;

  __shared__ __align__(16) char smem[32768];

  const int tid = threadIdx.x;
  const int wv = tid >> 6, lane = tid & 63;
  const int l15 = lane & 15;
  const int wr = wv >> 1, wc = wv & 1;

  const int rA0 = (wv * 2 + 0) * 16 + (lane >> 2);
  const int rA1 = (wv * 2 + 1) * 16 + (lane >> 2);
  const char* a_c = (const char*)hbuf;
  const char* b_c = (const char*)(w2t + (size_t)e * DDIM * HDIM);
  const int rc0 = (rA0 < mrem) ? rA0 : (mrem - 1);
  const int rc1 = (rA1 < mrem) ? rA1 : (mrem - 1);
  const size_t khb = (size_t)kh * ((HDIM / NSPLIT) * 2);   // K-quarter byte offset
  const char* ap0 = a_c + (size_t)(off0 + m0 + rc0) * (HDIM * 2) + khb
                        + (((lane & 3) ^ ((rA0 >> 1) & 3)) << 4);
  const char* ap1 = a_c + (size_t)(off0 + m0 + rc1) * (HDIM * 2) + khb
                        + (((lane & 3) ^ ((rA1 >> 1) & 3)) << 4);
  const char* bp0 = b_c + (size_t)(n0 + rA0) * (HDIM * 2) + khb
                        + (((lane & 3) ^ ((rA0 >> 1) & 3)) << 4);
  const char* bp1 = b_c + (size_t)(n0 + rA1) * (HDIM * 2) + khb
                        + (((lane & 3) ^ ((rA1 >> 1) & 3)) << 4);
  char* ldsA0 = smem + (wv * 2 + 0) * 1024;
  char* ldsA1 = smem + (wv * 2 + 1) * 1024;
  char* ldsB0 = smem + 16384 + (wv * 2 + 0) * 1024;
  char* ldsB1 = smem + 16384 + (wv * 2 + 1) * 1024;

  const unsigned foff = (unsigned)(((lane >> 4) ^ ((l15 >> 1) & 3)) << 4);

  f32x4 acc[4][4] = {};
  const int NT = (HDIM / NSPLIT) / BKK;   // 32

  gload16(ap0, ldsA0); gload16(ap1, ldsA1);
  gload16(bp0, ldsB0); gload16(bp1, ldsB1);

#pragma unroll 2
  for (int ks = 0; ks < NT; ++ks) {
    const int cur = ks & 1;
    if (ks + 1 < NT) {
      const int nb = (cur ^ 1) * 8192;
      const size_t kb = (size_t)(ks + 1) * 64;
      gload16(ap0 + kb, ldsA0 + nb); gload16(ap1 + kb, ldsA1 + nb);
      gload16(bp0 + kb, ldsB0 + nb); gload16(bp1 + kb, ldsB1 + nb);
      asm volatile("s_waitcnt vmcnt(4)" ::: "memory");
    } else {
      asm volatile("s_waitcnt vmcnt(0)" ::: "memory");
    }
    __builtin_amdgcn_sched_barrier(0);
    __builtin_amdgcn_s_barrier();
    const char* Ab = smem + cur * 8192;
    const char* Bb = smem + 16384 + cur * 8192;
    f16x8 af[4], bfr[4];
#pragma unroll
    for (int m = 0; m < 4; ++m)
      af[m] = *(const f16x8*)(Ab + (wr * 64 + m * 16 + l15) * 64 + foff);
#pragma unroll
    for (int n = 0; n < 4; ++n)
      bfr[n] = *(const f16x8*)(Bb + (wc * 64 + n * 16 + l15) * 64 + foff);
#pragma unroll
    for (int m = 0; m < 4; ++m)
#pragma unroll
      for (int n = 0; n < 4; ++n)
        acc[m][n] = __builtin_amdgcn_mfma_f32_16x16x32_f16(af[m], bfr[n], acc[m][n], 0, 0, 0);
    __builtin_amdgcn_sched_barrier(0);
    __builtin_amdgcn_s_barrier();
  }

  if (YB) {
    _Float16* ypart = yb + (size_t)kh * NPAIR * DDIM;
#pragma unroll
    for (int m = 0; m < 4; ++m) {
#pragma unroll
      for (int j = 0; j < 4; ++j) {
        int row = wr * 64 + m * 16 + (lane >> 4) * 4 + j;
#pragma unroll
        for (int n = 0; n < 4; ++n) {
          int col = wc * 64 + n * 16 + l15;
          *(_Float16*)(smem + (row << 8) + (((col << 1) ^ ((row & 15) << 4)))) =
              (_Float16)acc[m][n][j];
        }
      }
    }
    __syncthreads();
    const int srow = tid >> 1, half = tid & 1;
    if (srow < mrem) {
      _Float16* yr = ypart + (size_t)(off0 + m0 + srow) * DDIM + n0 + half * 64;
#pragma unroll
      for (int i = 0; i < 8; ++i) {
        f16x8 v = *(const f16x8*)(smem + (srow << 8) + (((half * 128 + i * 16) ^ ((srow & 15) << 4))));
        *(f16x8*)(yr + i * 8) = v;
      }
    }
  } else {
    float bias[4];
#pragma unroll
    for (int n = 0; n < 4; ++n)
      bias[n] = (kh == 0) ? b2[(size_t)e * DDIM + n0 + wc * 64 + n * 16 + l15] : 0.f;
#pragma unroll
    for (int m = 0; m < 4; ++m) {
#pragma unroll
      for (int j = 0; j < 4; ++j) {
        int row = wr * 64 + m * 16 + (lane >> 4) * 4 + j;
        if (row < mrem) {
          int g = off0 + m0 + row;
          float wgt = row_w[g];
          float* op = out + (size_t)row_token[g] * DDIM + n0 + wc * 64 + l15;
#pragma unroll
          for (int n = 0; n < 4; ++n)
            atomicAdd(op + n * 16, wgt * (acc[m][n][j] + bias[n]));
        }
      }
    }
  }
}

// ---------------- combine: out[t] = sum_k tw[t,k] * (sum_p y_p[g_k] + b2[e_k]) ----------------
__global__ __launch_bounds__(256) void k_combine(const _Float16* __restrict__ yb,
    const int* __restrict__ inv, const int* __restrict__ tidx,
    const float* __restrict__ tw, const float* __restrict__ b2,
    float* __restrict__ out) {
  const int t  = blockIdx.x * 2 + (threadIdx.x >> 7);
  const int c8 = (threadIdx.x & 127) * 8;
  const int g0 = inv[2 * t],  g1 = inv[2 * t + 1];
  const int e0 = tidx[2 * t], e1 = tidx[2 * t + 1];
  const float w0 = tw[2 * t], w1 = tw[2 * t + 1];
  float s0[8] = {0,0,0,0,0,0,0,0}, s1[8] = {0,0,0,0,0,0,0,0};
#pragma unroll
  for (int p = 0; p < NSPLIT; ++p) {
    const _Float16* yp = yb + (size_t)p * NPAIR * DDIM;
    f16x8 a = *(const f16x8*)(yp + (size_t)g0 * DDIM + c8);
    f16x8 b = *(const f16x8*)(yp + (size_t)g1 * DDIM + c8);
#pragma unroll
    for (int i = 0; i < 8; ++i) { s0[i] += (float)a[i]; s1[i] += (float)b[i]; }
  }
  float o[8];
#pragma unroll
  for (int i = 0; i < 8; ++i) {
    float bA = b2[(size_t)e0 * DDIM + c8 + i];
    float bB = b2[(size_t)e1 * DDIM + c8 + i];
    o[i] = w0 * (s0[i] + bA) + w1 * (s1[i] + bB);
  }
  float* op = out + (size_t)t * DDIM + c8;
  *(float4*)op       = make_float4(o[0], o[1], o[2], o[3]);
  *(float4*)(op + 4) = make_float4(o[4], o[5], o[6], o[7]);
}

// ---------------- host ----------------
extern "C" void kernel_launch(void* const* d_in, const int* in_sizes, int n_in,
                              void* d_out, int out_size, void* d_ws, size_t ws_size,
                              hipStream_t stream) {
  const float* x  = (const float*)d_in[0];
  const float* rw = (const float*)d_in[1];
  const float* rb = (const float*)d_in[2];
  const float* w1 = (const float*)d_in[3];
  const float* b1 = (const float*)d_in[4];
  const float* w2 = (const float*)d_in[5];
  const float* b2 = (const float*)d_in[6];
  float* out = (float*)d_out;
  char* ws = (char*)d_ws;

  int*      tidx    = (int*)(ws + 0);               // 32KB
  float*    tw      = (float*)(ws + 32768);         // 32KB
  int*      offs    = (int*)(ws + 65792);
  int*      row_tok = (int*)(ws + 66048);           // 32KB
  float*    row_w   = (float*)(ws + 98816);         // 32KB
  int*      inv     = (int*)(ws + 131584);          // 32KB
  _Float16* xb      = (_Float16*)(ws + 164352);     // 8MB
  _Float16* wt      = (_Float16*)(ws + 8552960);    // 64MB (w1t then w2t)
  _Float16* hb      = (_Float16*)(ws + 75661824);   // 64MB
  _Float16* yb      = (_Float16*)(ws + 142770688);  // 64MB (4 x 16MB partials)
  const bool big = ws_size >= 209879552ULL;

  if (!big) hipMemsetAsync(out, 0, (size_t)TOK * DDIM * sizeof(float), stream);

  k_router<<<dim3(TOK / 4), 256, 0, stream>>>(x, rw, rb, tidx, tw, xb);
  k_scan<<<dim3(1), 1024, 0, stream>>>(tidx, tw, offs, row_tok, row_w, inv);
  k_transpose<<<dim3(HDIM / 64, DDIM / 64, NEXP), 256, 0, stream>>>(w1, wt, DDIM, HDIM);
  k_gemm1<<<dim3(HDIM / BN, TOK / BM, NEXP), 256, 0, stream>>>(xb, wt, b1, offs, row_tok, hb);
  k_transpose<<<dim3(DDIM / 64, HDIM / 64, NEXP), 256, 0, stream>>>(w2, wt, HDIM, DDIM);
  if (big) {
    k_gemm2<true><<<dim3(DDIM / BN, TOK / BM, NEXP * NSPLIT), 256, 0, stream>>>(
        hb, wt, b2, offs, row_tok, row_w, yb, out);
    k_combine<<<dim3(TOK / 2), 256, 0, stream>>>(yb, inv, tidx, tw, b2, out);
  } else {
    k_gemm2<false><<<dim3(DDIM / BN, TOK / BM, NEXP * NSPLIT), 256, 0, stream>>>(
        hb, wt, b2, offs, row_tok, row_w, yb, out);
  }
}